// Round 17
// baseline (820.428 us; speedup 1.0000x reference)
//
#include <hip/hip_runtime.h>

#define NODES   30000
#define E0N     480000
#define ETOT    510000   // E0N + NODES self loops
#define D0      100
#define WDIM    300      // H*F = 3*100
#define NW      600      // dual output width
#define NEG     0.2f
#define XLP     384      // head-major padded xl row: 3 heads x 128 (bf16 elems)
#define NBIN    1024

typedef __bf16 bf16x8 __attribute__((ext_vector_type(8)));
typedef float  f32x4  __attribute__((ext_vector_type(4)));
typedef float  f32x2  __attribute__((ext_vector_type(2)));
#define BCAST2(x) ((f32x2){(x), (x)})

// ---------------- CSR build ----------------
__global__ void count_edges(const int* __restrict__ ei, int* __restrict__ counts) {
    int e = blockIdx.x * 256 + threadIdx.x;
    if (e >= ETOT) return;
    int d = (e < E0N) ? ei[E0N + e] : (e - E0N);
    atomicAdd(&counts[d], 1);
}

__global__ __launch_bounds__(1024) void scan_kernel(const int* __restrict__ counts,
                                                    int* __restrict__ offsets, int n) {
    __shared__ int lds[1024];
    const int CH = 32;
    int t = threadIdx.x;
    int base = t * CH;
    int loc[CH];
    int sum = 0;
    #pragma unroll
    for (int i = 0; i < CH; i++) {
        int v = (base + i < n) ? counts[base + i] : 0;
        loc[i] = sum;
        sum += v;
    }
    lds[t] = sum;
    __syncthreads();
    for (int off = 1; off < 1024; off <<= 1) {
        int v = (t >= off) ? lds[t - off] : 0;
        __syncthreads();
        lds[t] += v;
        __syncthreads();
    }
    int ex = (t == 0) ? 0 : lds[t - 1];
    #pragma unroll
    for (int i = 0; i < CH; i++) {
        int idx = base + i;
        if (idx < n) offsets[idx] = ex + loc[i];
    }
    if (t == 0) offsets[n] = lds[1023];
}

// stores PRE-SCALED element offsets (src * XLP) for direct agg addressing
__global__ void scatter_edges(const int* __restrict__ ei, const int* __restrict__ offsets,
                              int* __restrict__ cursor, int* __restrict__ csr_off) {
    int e = blockIdx.x * 256 + threadIdx.x;
    if (e >= ETOT) return;
    int s, d;
    if (e < E0N) { s = ei[e]; d = ei[E0N + e]; }
    else         { s = e - E0N; d = s; }
    int pos = offsets[d] + atomicAdd(&cursor[d], 1);
    csr_off[pos] = s * XLP;
}

// ---------------- degree sort (descending) for balanced agg blocks ----------
__global__ void hist_deg(const int* __restrict__ counts, int* __restrict__ hist) {
    __shared__ int lh[NBIN];
    for (int i = threadIdx.x; i < NBIN; i += 256) lh[i] = 0;
    __syncthreads();
    int n = blockIdx.x * 256 + threadIdx.x;
    if (n < NODES) {
        int d = counts[n]; if (d > NBIN - 1) d = NBIN - 1;
        atomicAdd(&lh[NBIN - 1 - d], 1);
    }
    __syncthreads();
    for (int i = threadIdx.x; i < NBIN; i += 256) {
        int v = lh[i];
        if (v) atomicAdd(&hist[i], v);
    }
}

__global__ void scatter_deg(const int* __restrict__ counts, const int* __restrict__ doffs,
                            int* __restrict__ dcur, int* __restrict__ order) {
    __shared__ int lcnt[NBIN];
    __shared__ int lbase[NBIN];
    for (int i = threadIdx.x; i < NBIN; i += 256) lcnt[i] = 0;
    __syncthreads();
    int n = blockIdx.x * 256 + threadIdx.x;
    int bin = 0, rank = 0;
    bool act = n < NODES;
    if (act) {
        int d = counts[n]; if (d > NBIN - 1) d = NBIN - 1;
        bin = NBIN - 1 - d;
        rank = atomicAdd(&lcnt[bin], 1);
    }
    __syncthreads();
    for (int i = threadIdx.x; i < NBIN; i += 256) {
        int c = lcnt[i];
        lbase[i] = c ? atomicAdd(&dcur[i], c) : 0;
    }
    __syncthreads();
    if (act) order[doffs[bin] + lbase[bin] + rank] = n;
}

// ---------------- all-layer B fragment pre-split (one launch) ----------------
__device__ __forceinline__ void bfrag_one(const float* Bl, const float* Br,
                                          bf16x8* out, int K, int t) {
    int lane = t & 63;
    int n16  = (t >> 6) % 40;
    int s    = t / (64 * 40);
    int c = n16 * 16 + (lane & 15);
    union { bf16x8 v; __bf16 e[8]; } hi, lo;
    #pragma unroll
    for (int j = 0; j < 8; j++) {
        int k = s * 32 + ((lane >> 4) * 8) + j;
        float x = 0.f;
        if (k < K && c < NW)
            x = (c < WDIM) ? Bl[(size_t)k * WDIM + c] : Br[(size_t)k * WDIM + c - WDIM];
        __bf16 h = (__bf16)x;
        hi.e[j] = h;
        lo.e[j] = (__bf16)(x - (float)h);
    }
    size_t base = ((size_t)(s * 40 + n16) * 2) * 64 + lane;
    out[base]      = hi.v;
    out[base + 64] = lo.v;
}

__global__ void make_bfrag_all(const float* __restrict__ Wl0, const float* __restrict__ Wr0,
                               const float* __restrict__ Wl, const float* __restrict__ Wr,
                               bf16x8* __restrict__ frag0, bf16x8* __restrict__ frag1,
                               size_t fragstride) {
    int t = blockIdx.x * 256 + threadIdx.x;
    const int L0 = 4 * 40 * 64, LN = 10 * 40 * 64;
    if (t < L0) {
        bfrag_one(Wl0, Wr0, frag0, D0, t);
    } else {
        int u = t - L0;
        int layer = u / LN;
        if (layer >= 4) return;
        bfrag_one(Wl + (size_t)layer * WDIM * WDIM, Wr + (size_t)layer * WDIM * WDIM,
                  frag1 + layer * fragstride, WDIM, u - layer * LN);
    }
}

// ---------------- MFMA dual GEMM: 512 threads, 128 rows x 256 cols per block --
// A staged once per block (3 col-groups instead of 5 -> 40% less split VALU).
__global__ __launch_bounds__(512) void gemm_mfma(
    const float* __restrict__ A, const int* __restrict__ xmap, int use_map,
    const bf16x8* __restrict__ Bfrag,
    const float* __restrict__ bl, const float* __restrict__ br,
    ushort* __restrict__ Cl16, float* __restrict__ Cr,
    int M, int K, int ksteps) {

    __shared__ bf16x8 Alds[8][2][64];

    int id = blockIdx.x;
    int w8 = id % 24;
    int mb = (w8 & 7) + 8 * (id / 24);
    int cbg = w8 >> 3;               // 0..2 (cols cbg*256 .. +256)
    if (mb >= 235) return;

    int tid  = threadIdx.x;
    int lane = tid & 63;
    int wid  = tid >> 6;             // 0..7
    int wm = wid >> 2;               // 0..1 : row half
    int wn = wid & 3;                // 0..3 : 64-col slice
    int row0 = mb * 128;
    bool active_n = (cbg * 16 + wn * 4) < 40;   // n16 range guard (600-col tail)

    f32x4 acc[4][4] = {};

    for (int s = 0; s < ksteps; s++) {
        int kt = s * 32;
        {   // A stage: 512 tuples, one per thread
            int m16  = tid >> 6;
            int slot = tid & 63;
            int kh = slot >> 4, rl = slot & 15;
            int gr = row0 + m16 * 16 + rl;
            int gc = kt + kh * 8;
            float4 v0 = make_float4(0.f,0.f,0.f,0.f), v1 = v0;
            if (gr < M) {
                int ar = use_map ? xmap[gr] : gr;
                const float* ap = A + (size_t)ar * K + gc;
                if (gc + 4 <= K) v0 = *(const float4*)ap;
                if (gc + 8 <= K) v1 = *(const float4*)(ap + 4);
            }
            union { bf16x8 v; __bf16 e[8]; } hi, lo;
            const float* xs0 = (const float*)&v0;
            const float* xs1 = (const float*)&v1;
            #pragma unroll
            for (int j = 0; j < 8; j++) {
                float x = (j < 4) ? xs0[j] : xs1[j - 4];
                __bf16 h = (__bf16)x;
                hi.e[j] = h;
                lo.e[j] = (__bf16)(x - (float)h);
            }
            Alds[m16][0][slot] = hi.v;
            Alds[m16][1][slot] = lo.v;
        }
        // B fragments: direct global->reg (coalesced, L2-hot)
        bf16x8 bfr[4][2];
        if (active_n) {
            const bf16x8* bwave = Bfrag + ((size_t)(s * 40 + cbg * 16 + wn * 4) * 2) * 64;
            #pragma unroll
            for (int n = 0; n < 4; n++) {
                bfr[n][0] = bwave[(n * 2 + 0) * 64 + lane];
                bfr[n][1] = bwave[(n * 2 + 1) * 64 + lane];
            }
        }
        __syncthreads();

        if (active_n) {
            bf16x8 af[4][2];
            #pragma unroll
            for (int m = 0; m < 4; m++) {
                af[m][0] = Alds[wm * 4 + m][0][lane];
                af[m][1] = Alds[wm * 4 + m][1][lane];
            }
            #pragma unroll
            for (int m = 0; m < 4; m++)
                #pragma unroll
                for (int n = 0; n < 4; n++) {
                    acc[m][n] = __builtin_amdgcn_mfma_f32_16x16x32_bf16(af[m][1], bfr[n][0], acc[m][n], 0, 0, 0);
                    acc[m][n] = __builtin_amdgcn_mfma_f32_16x16x32_bf16(af[m][0], bfr[n][1], acc[m][n], 0, 0, 0);
                    acc[m][n] = __builtin_amdgcn_mfma_f32_16x16x32_bf16(af[m][0], bfr[n][0], acc[m][n], 0, 0, 0);
                }
        }
        __syncthreads();
    }

    if (!active_n) return;
    int r0 = row0 + wm * 64;
    int c0 = cbg * 256 + wn * 64;
    #pragma unroll
    for (int m = 0; m < 4; m++)
        #pragma unroll
        for (int n = 0; n < 4; n++) {
            #pragma unroll
            for (int reg = 0; reg < 4; reg++) {
                int gr = r0 + m * 16 + (lane >> 4) * 4 + reg;
                int gc = c0 + n * 16 + (lane & 15);
                if (gr < M && gc < NW) {
                    if (gc < WDIM) {
                        float v = acc[m][n][reg] + bl[gc];
                        int head = gc / 100;
                        int fh = gc - head * 100;
                        __bf16 b = (__bf16)v;
                        Cl16[(size_t)gr * XLP + head * 128 + fh] = *(ushort*)&b;
                    } else {
                        int cc = gc - WDIM;
                        Cr[(size_t)gr * WDIM + cc] = acc[m][n][reg] + br[cc];
                    }
                }
            }
        }
}

// ---------------- fused GAT: parity-packed reduce, degree-sorted nodes ----
__device__ __forceinline__ f32x2 bf2f2(unsigned u) {
    f32x2 r;
    r.x = __uint_as_float(u << 16);
    r.y = __uint_as_float(u & 0xffff0000u);
    return r;
}
__device__ __forceinline__ f32x2 lrelu2(f32x2 t) {
    return __builtin_elementwise_max(t, t * BCAST2(NEG));
}

__global__ __launch_bounds__(256) void gat_edge_agg(
    const ushort* __restrict__ xl, const float* __restrict__ xr,
    const int* __restrict__ offsets, const int* __restrict__ csr_off,
    const int* __restrict__ order,
    const float* __restrict__ att, const float* __restrict__ bias,
    float* __restrict__ fout) {
    __shared__ float st[4][64][10];
    int wid  = threadIdx.x >> 6;
    int lane = threadIdx.x & 63;
    int node = order[blockIdx.x * 2 + (wid >> 1)];
    int sub  = wid & 1;
    int lq    = lane & 31;
    int headq = lane >> 5;   // 0 or 1
    int par   = lane & 1;

    f32x2 aw4[2] = {}, xr4[2] = {}, awp = {}, xrp = {};
    if (lq < 25) {
        float4 a = *(const float4*)(att + headq * 100 + 4 * lq);
        float4 b = *(const float4*)(xr + (size_t)node * WDIM + headq * 100 + 4 * lq);
        aw4[0] = (f32x2){a.x, a.y}; aw4[1] = (f32x2){a.z, a.w};
        xr4[0] = (f32x2){b.x, b.y}; xr4[1] = (f32x2){b.z, b.w};
    }
    if (lane < 50) {
        float2 a = *(const float2*)(att + 200 + 2 * lane);
        float2 b = *(const float2*)(xr + (size_t)node * WDIM + 200 + 2 * lane);
        awp = (f32x2){a.x, a.y};
        xrp = (f32x2){b.x, b.y};
    }

    float m_h = -1e38f, s_h = 0.f, m_2 = -1e38f, s_2 = 0.f;  // s parity-packed
    f32x2 acc4[2] = {}, accp = {};

    int beg = offsets[node], end = offsets[node + 1];
    int half = (end - beg + 1) >> 1;
    int lo = beg + sub * half;
    int iend = sub ? end : beg + half;

    for (int i = lo; i < iend; i += 2) {
        bool act_b = (i + 1) < iend;
        int oa = csr_off[i];
        int ob = csr_off[act_b ? i + 1 : i];
        uint2 ua = *(const uint2*)(xl + oa + 4 * lane);
        uint2 ub = *(const uint2*)(xl + ob + 4 * lane);
        unsigned pa = *(const unsigned*)(xl + oa + 256 + 2 * lane);
        unsigned pb = *(const unsigned*)(xl + ob + 256 + 2 * lane);

        f32x2 va0 = bf2f2(ua.x), va1 = bf2f2(ua.y), vap = bf2f2(pa);
        f32x2 vb0 = bf2f2(ub.x), vb1 = bf2f2(ub.y), vbp = bf2f2(pb);

        // packed dot: q = sum(lrelu(v+xr)*aw)
        f32x2 tA = __builtin_elementwise_fma(lrelu2(va0 + xr4[0]), aw4[0],
                                             lrelu2(va1 + xr4[1]) * aw4[1]);
        f32x2 tB = __builtin_elementwise_fma(lrelu2(vb0 + xr4[0]), aw4[0],
                                             lrelu2(vb1 + xr4[1]) * aw4[1]);
        f32x2 tA2 = lrelu2(vap + xrp) * awp;
        f32x2 tB2 = lrelu2(vbp + xrp) * awp;
        float qA  = tA.x + tA.y,   qB  = tB.x + tB.y;
        float qA2 = tA2.x + tA2.y, qB2 = tB2.x + tB2.y;

        // parity-packed reduce: stage1 per edge, pack by lane&1, shared stages
        qA += __shfl_xor(qA, 1, 64);   qB += __shfl_xor(qB, 1, 64);
        float u = par ? qB : qA;
        u += __shfl_xor(u, 2, 64);
        u += __shfl_xor(u, 4, 64);
        u += __shfl_xor(u, 8, 64);
        u += __shfl_xor(u, 16, 64);            // u: qA(even)/qB(odd), per half
        qA2 += __shfl_xor(qA2, 1, 64); qB2 += __shfl_xor(qB2, 1, 64);
        float v = par ? qB2 : qA2;
        v += __shfl_xor(v, 2, 64);
        v += __shfl_xor(v, 4, 64);
        v += __shfl_xor(v, 8, 64);
        v += __shfl_xor(v, 16, 64);
        v += __shfl_xor(v, 32, 64);            // v: qA2(even)/qB2(odd)
        if (!act_b && par) { u = -3e38f; v = -3e38f; }  // kill dead B stream

        float upair = fmaxf(u, __shfl_xor(u, 1, 64));   // pair-uniform max
        float vpair = fmaxf(v, __shfl_xor(v, 1, 64));

        // defer-rescale (THR=8); m uniform, s/acc scale shared
        if (__any(upair > m_h + 8.f || vpair > m_2 + 8.f)) {
            float nm_h = fmaxf(m_h, upair), nm_2 = fmaxf(m_2, vpair);
            float e_h = __expf(m_h - nm_h), e_2 = __expf(m_2 - nm_2);
            s_h *= e_h; s_2 *= e_2;
            acc4[0] *= BCAST2(e_h); acc4[1] *= BCAST2(e_h);
            accp *= BCAST2(e_2);
            m_h = nm_h; m_2 = nm_2;
        }
        float cu = __expf(u - m_h);   // packed coefficient (0 for dead stream)
        float cv = __expf(v - m_2);
        s_h += cu; s_2 += cv;         // parity-packed sums
        float cup = __shfl_xor(cu, 1, 64), cvp = __shfl_xor(cv, 1, 64);
        float cA  = par ? cup : cu;
        float cB  = par ? cu  : cup;
        float cA2 = par ? cvp : cv;
        float cB2 = par ? cv  : cvp;
        acc4[0] = __builtin_elementwise_fma(BCAST2(cA), va0, acc4[0]);
        acc4[1] = __builtin_elementwise_fma(BCAST2(cA), va1, acc4[1]);
        acc4[0] = __builtin_elementwise_fma(BCAST2(cB), vb0, acc4[0]);
        acc4[1] = __builtin_elementwise_fma(BCAST2(cB), vb1, acc4[1]);
        accp    = __builtin_elementwise_fma(BCAST2(cA2), vap, accp);
        accp    = __builtin_elementwise_fma(BCAST2(cB2), vbp, accp);
    }

    // merge parity-packed sums before publishing
    s_h += __shfl_xor(s_h, 1, 64);
    s_2 += __shfl_xor(s_2, 1, 64);

    // publish partial state
    st[wid][lane][0] = m_h; st[wid][lane][1] = s_h;
    st[wid][lane][2] = m_2; st[wid][lane][3] = s_2;
    st[wid][lane][4] = acc4[0].x; st[wid][lane][5] = acc4[0].y;
    st[wid][lane][6] = acc4[1].x; st[wid][lane][7] = acc4[1].y;
    st[wid][lane][8] = accp.x;    st[wid][lane][9] = accp.y;
    __syncthreads();
    if (sub) return;

    // exact merge with partner wave (lane-local, no shuffles)
    const float* p = st[wid ^ 1][lane];
    float pm_h = p[0], ps_h = p[1], pm_2 = p[2], ps_2 = p[3];

    float M_h = fmaxf(m_h, pm_h);
    float ea_h = __expf(m_h - M_h), eb_h = __expf(pm_h - M_h);
    float inv_h = 1.f / (s_h * ea_h + ps_h * eb_h);
    float M_2 = fmaxf(m_2, pm_2);
    float ea_2 = __expf(m_2 - M_2), eb_2 = __expf(pm_2 - M_2);
    float inv_2 = 1.f / (s_2 * ea_2 + ps_2 * eb_2);

    if (lq < 25) {
        float4 bv = *(const float4*)(bias + headq * 100 + 4 * lq);
        float4 o;
        o.x = fmaxf((acc4[0].x * ea_h + p[4] * eb_h) * inv_h + bv.x, 0.f);
        o.y = fmaxf((acc4[0].y * ea_h + p[5] * eb_h) * inv_h + bv.y, 0.f);
        o.z = fmaxf((acc4[1].x * ea_h + p[6] * eb_h) * inv_h + bv.z, 0.f);
        o.w = fmaxf((acc4[1].y * ea_h + p[7] * eb_h) * inv_h + bv.w, 0.f);
        *(float4*)(fout + (size_t)node * WDIM + headq * 100 + 4 * lq) = o;
    }
    if (lane < 50) {
        float2 bv = *(const float2*)(bias + 200 + 2 * lane);
        float2 o;
        o.x = fmaxf((accp.x * ea_2 + p[8] * eb_2) * inv_2 + bv.x, 0.f);
        o.y = fmaxf((accp.y * ea_2 + p[9] * eb_2) * inv_2 + bv.y, 0.f);
        *(float2*)(fout + (size_t)node * WDIM + 200 + 2 * lane) = o;
    }
}

// ---------------- host ----------------
static inline size_t align256(size_t x) { return (x + 255) & ~(size_t)255; }

extern "C" void kernel_launch(void* const* d_in, const int* in_sizes, int n_in,
                              void* d_out, int out_size, void* d_ws, size_t ws_size,
                              hipStream_t stream) {
    const int*   x     = (const int*)d_in[0];
    const int*   ei    = (const int*)d_in[1];
    const float* emb   = (const float*)d_in[2];
    const float* Wl0   = (const float*)d_in[3];
    const float* bl0   = (const float*)d_in[4];
    const float* Wr0   = (const float*)d_in[5];
    const float* br0   = (const float*)d_in[6];
    const float* att0  = (const float*)d_in[7];
    const float* bias0 = (const float*)d_in[8];
    const float* Wl    = (const float*)d_in[9];
    const float* bl    = (const float*)d_in[10];
    const float* Wr    = (const float*)d_in[11];
    const float* br    = (const float*)d_in[12];
    const float* att   = (const float*)d_in[13];
    const float* bias  = (const float*)d_in[14];

    char* ws = (char*)d_ws;
    size_t off = 0;
    float* h      = (float*)(ws + off);  off = align256(off + (size_t)NODES * WDIM * 4);
    ushort* xlb16 = (ushort*)(ws + off); off = align256(off + (size_t)NODES * XLP * 2);
    float* xrb    = (float*)(ws + off);  off = align256(off + (size_t)NODES * WDIM * 4);
    int* counts   = (int*)(ws + off);    off = align256(off + (size_t)NODES * 4);
    int* cursor   = (int*)(ws + off);    off = align256(off + (size_t)NODES * 4);
    int* offsets  = (int*)(ws + off);    off = align256(off + (size_t)(NODES + 1) * 4);
    int* csr_off  = (int*)(ws + off);    off = align256(off + (size_t)ETOT * 4);
    int* hist     = (int*)(ws + off);    off = align256(off + (size_t)NBIN * 4);
    int* dcur     = (int*)(ws + off);    off = align256(off + (size_t)NBIN * 4);
    int* doffs    = (int*)(ws + off);    off = align256(off + (size_t)(NBIN + 1) * 4);
    int* order    = (int*)(ws + off);    off = align256(off + (size_t)NODES * 4);
    size_t frag_l0_elems = (size_t)4 * 40 * 2 * 64;    // bf16x8 units
    size_t frag_ln_elems = (size_t)10 * 40 * 2 * 64;
    bf16x8* bfrag0 = (bf16x8*)(ws + off); off = align256(off + frag_l0_elems * 16);
    bf16x8* bfrag1 = (bf16x8*)(ws + off); off = align256(off + 4 * frag_ln_elems * 16);

    float* out = (float*)d_out;

    // all weight fragment pre-splits in ONE launch
    {
        int total = 4 * 40 * 64 + 4 * 10 * 40 * 64;
        make_bfrag_all<<<(total + 255) / 256, 256, 0, stream>>>(
            Wl0, Wr0, Wl, Wr, bfrag0, bfrag1, frag_ln_elems);
    }

    // CSR build
    hipMemsetAsync(counts, 0, (size_t)NODES * 4, stream);
    hipMemsetAsync(cursor, 0, (size_t)NODES * 4, stream);
    hipMemsetAsync(hist, 0, (size_t)NBIN * 4, stream);
    hipMemsetAsync(dcur, 0, (size_t)NBIN * 4, stream);
    count_edges<<<(ETOT + 255) / 256, 256, 0, stream>>>(ei, counts);
    scan_kernel<<<1, 1024, 0, stream>>>(counts, offsets, NODES);
    scatter_edges<<<(ETOT + 255) / 256, 256, 0, stream>>>(ei, offsets, cursor, csr_off);

    // degree sort (descending) for balanced agg blocks
    hist_deg<<<(NODES + 255) / 256, 256, 0, stream>>>(counts, hist);
    scan_kernel<<<1, 1024, 0, stream>>>(hist, doffs, NBIN);
    scatter_deg<<<(NODES + 255) / 256, 256, 0, stream>>>(counts, doffs, dcur, order);

    int agg_blocks = NODES / 2;    // 2 nodes per block (NODES even)
    int gemm_grid  = 30 * 24;      // ceil(235/8) octets x (8 mb x 3 cbg)

    // layer 0: A = emb with row indirection
    gemm_mfma<<<gemm_grid, 512, 0, stream>>>(emb, x, 1, bfrag0, bl0, br0, xlb16, xrb, NODES, D0, 4);
    gat_edge_agg<<<agg_blocks, 256, 0, stream>>>(xlb16, xrb, offsets, csr_off, order,
                                                 att0, bias0, h);

    // layers 1..4
    for (int i = 0; i < 4; i++) {
        float* dst = (i == 3) ? out : h;
        gemm_mfma<<<gemm_grid, 512, 0, stream>>>(h, nullptr, 0, bfrag1 + i * frag_ln_elems,
                                                 bl + i * WDIM, br + i * WDIM,
                                                 xlb16, xrb, NODES, WDIM, 10);
        gat_edge_agg<<<agg_blocks, 256, 0, stream>>>(xlb16, xrb, offsets, csr_off, order,
                                                     att + (size_t)i * WDIM,
                                                     bias + (size_t)i * WDIM, dst);
    }
}

// Round 18
// 800.953 us; speedup vs baseline: 1.0243x; 1.0243x over previous
//
#include <hip/hip_runtime.h>

#define NODES   30000
#define E0N     480000
#define ETOT    510000   // E0N + NODES self loops
#define D0      100
#define WDIM    300      // H*F = 3*100
#define NW      600      // dual output width
#define NEG     0.2f
#define XLP     384      // head-major padded xl row: 3 heads x 128 (bf16 elems)
#define NBIN    1024

typedef __bf16 bf16x8 __attribute__((ext_vector_type(8)));
typedef float  f32x4  __attribute__((ext_vector_type(4)));
typedef float  f32x2  __attribute__((ext_vector_type(2)));
#define BCAST2(x) ((f32x2){(x), (x)})

// ---------------- CSR build ----------------
__global__ void count_edges(const int* __restrict__ ei, int* __restrict__ counts) {
    int e = blockIdx.x * 256 + threadIdx.x;
    if (e >= ETOT) return;
    int d = (e < E0N) ? ei[E0N + e] : (e - E0N);
    atomicAdd(&counts[d], 1);
}

__global__ __launch_bounds__(1024) void scan_kernel(const int* __restrict__ counts,
                                                    int* __restrict__ offsets, int n) {
    __shared__ int lds[1024];
    const int CH = 32;
    int t = threadIdx.x;
    int base = t * CH;
    int loc[CH];
    int sum = 0;
    #pragma unroll
    for (int i = 0; i < CH; i++) {
        int v = (base + i < n) ? counts[base + i] : 0;
        loc[i] = sum;
        sum += v;
    }
    lds[t] = sum;
    __syncthreads();
    for (int off = 1; off < 1024; off <<= 1) {
        int v = (t >= off) ? lds[t - off] : 0;
        __syncthreads();
        lds[t] += v;
        __syncthreads();
    }
    int ex = (t == 0) ? 0 : lds[t - 1];
    #pragma unroll
    for (int i = 0; i < CH; i++) {
        int idx = base + i;
        if (idx < n) offsets[idx] = ex + loc[i];
    }
    if (t == 0) offsets[n] = lds[1023];
}

// stores PRE-SCALED element offsets (src * XLP) for direct agg addressing
__global__ void scatter_edges(const int* __restrict__ ei, const int* __restrict__ offsets,
                              int* __restrict__ cursor, int* __restrict__ csr_off) {
    int e = blockIdx.x * 256 + threadIdx.x;
    if (e >= ETOT) return;
    int s, d;
    if (e < E0N) { s = ei[e]; d = ei[E0N + e]; }
    else         { s = e - E0N; d = s; }
    int pos = offsets[d] + atomicAdd(&cursor[d], 1);
    csr_off[pos] = s * XLP;
}

// ---------------- degree sort (descending) for balanced agg blocks ----------
__global__ void hist_deg(const int* __restrict__ counts, int* __restrict__ hist) {
    __shared__ int lh[NBIN];
    for (int i = threadIdx.x; i < NBIN; i += 256) lh[i] = 0;
    __syncthreads();
    int n = blockIdx.x * 256 + threadIdx.x;
    if (n < NODES) {
        int d = counts[n]; if (d > NBIN - 1) d = NBIN - 1;
        atomicAdd(&lh[NBIN - 1 - d], 1);
    }
    __syncthreads();
    for (int i = threadIdx.x; i < NBIN; i += 256) {
        int v = lh[i];
        if (v) atomicAdd(&hist[i], v);
    }
}

__global__ void scatter_deg(const int* __restrict__ counts, const int* __restrict__ doffs,
                            int* __restrict__ dcur, int* __restrict__ order) {
    __shared__ int lcnt[NBIN];
    __shared__ int lbase[NBIN];
    for (int i = threadIdx.x; i < NBIN; i += 256) lcnt[i] = 0;
    __syncthreads();
    int n = blockIdx.x * 256 + threadIdx.x;
    int bin = 0, rank = 0;
    bool act = n < NODES;
    if (act) {
        int d = counts[n]; if (d > NBIN - 1) d = NBIN - 1;
        bin = NBIN - 1 - d;
        rank = atomicAdd(&lcnt[bin], 1);
    }
    __syncthreads();
    for (int i = threadIdx.x; i < NBIN; i += 256) {
        int c = lcnt[i];
        lbase[i] = c ? atomicAdd(&dcur[i], c) : 0;
    }
    __syncthreads();
    if (act) order[doffs[bin] + lbase[bin] + rank] = n;
}

// ---------------- all-layer B fragment pre-split (one launch) ----------------
__device__ __forceinline__ void bfrag_one(const float* Bl, const float* Br,
                                          bf16x8* out, int K, int t) {
    int lane = t & 63;
    int n16  = (t >> 6) % 40;
    int s    = t / (64 * 40);
    int c = n16 * 16 + (lane & 15);
    union { bf16x8 v; __bf16 e[8]; } hi, lo;
    #pragma unroll
    for (int j = 0; j < 8; j++) {
        int k = s * 32 + ((lane >> 4) * 8) + j;
        float x = 0.f;
        if (k < K && c < NW)
            x = (c < WDIM) ? Bl[(size_t)k * WDIM + c] : Br[(size_t)k * WDIM + c - WDIM];
        __bf16 h = (__bf16)x;
        hi.e[j] = h;
        lo.e[j] = (__bf16)(x - (float)h);
    }
    size_t base = ((size_t)(s * 40 + n16) * 2) * 64 + lane;
    out[base]      = hi.v;
    out[base + 64] = lo.v;
}

__global__ void make_bfrag_all(const float* __restrict__ Wl0, const float* __restrict__ Wr0,
                               const float* __restrict__ Wl, const float* __restrict__ Wr,
                               bf16x8* __restrict__ frag0, bf16x8* __restrict__ frag1,
                               size_t fragstride) {
    int t = blockIdx.x * 256 + threadIdx.x;
    const int L0 = 4 * 40 * 64, LN = 10 * 40 * 64;
    if (t < L0) {
        bfrag_one(Wl0, Wr0, frag0, D0, t);
    } else {
        int u = t - L0;
        int layer = u / LN;
        if (layer >= 4) return;
        bfrag_one(Wl + (size_t)layer * WDIM * WDIM, Wr + (size_t)layer * WDIM * WDIM,
                  frag1 + layer * fragstride, WDIM, u - layer * LN);
    }
}

// ---------------- MFMA dual GEMM: xl(bf16 head-major) | xr(f32) = A@[Bl|Br]+b --
__global__ __launch_bounds__(256) void gemm_mfma(
    const float* __restrict__ A, const int* __restrict__ xmap, int use_map,
    const bf16x8* __restrict__ Bfrag,
    const float* __restrict__ bl, const float* __restrict__ br,
    ushort* __restrict__ Cl16, float* __restrict__ Cr,
    int M, int K, int ksteps) {

    __shared__ bf16x8 Alds[8][2][64];

    int id = blockIdx.x;
    int mb = (id & 7) + 8 * (id / 40);
    int cb = (id >> 3) % 5;
    if (mb >= 235) return;

    int tid  = threadIdx.x;
    int lane = tid & 63;
    int wid  = tid >> 6;
    int wm = wid >> 1, wn = wid & 1;
    int row0 = mb * 128;

    f32x4 acc[4][4] = {};

    for (int s = 0; s < ksteps; s++) {
        int kt = s * 32;
        #pragma unroll
        for (int u0 = 0; u0 < 2; u0++) {
            int u = u0 * 256 + tid;
            int m16  = u >> 6;
            int slot = u & 63;
            int kh = slot >> 4, rl = slot & 15;
            int gr = row0 + m16 * 16 + rl;
            int gc = kt + kh * 8;
            float4 v0 = make_float4(0.f,0.f,0.f,0.f), v1 = v0;
            if (gr < M) {
                int ar = use_map ? xmap[gr] : gr;
                const float* ap = A + (size_t)ar * K + gc;
                if (gc + 4 <= K) v0 = *(const float4*)ap;
                if (gc + 8 <= K) v1 = *(const float4*)(ap + 4);
            }
            union { bf16x8 v; __bf16 e[8]; } hi, lo;
            const float* xs0 = (const float*)&v0;
            const float* xs1 = (const float*)&v1;
            #pragma unroll
            for (int j = 0; j < 8; j++) {
                float x = (j < 4) ? xs0[j] : xs1[j - 4];
                __bf16 h = (__bf16)x;
                hi.e[j] = h;
                lo.e[j] = (__bf16)(x - (float)h);
            }
            Alds[m16][0][slot] = hi.v;
            Alds[m16][1][slot] = lo.v;
        }
        // B fragments: direct global->reg (coalesced, L2-hot)
        bf16x8 bfr[4][2];
        {
            const bf16x8* bwave = Bfrag + ((size_t)(s * 40 + cb * 8 + wn * 4) * 2) * 64;
            #pragma unroll
            for (int n = 0; n < 4; n++) {
                bfr[n][0] = bwave[(n * 2 + 0) * 64 + lane];
                bfr[n][1] = bwave[(n * 2 + 1) * 64 + lane];
            }
        }
        __syncthreads();

        bf16x8 af[4][2];
        #pragma unroll
        for (int m = 0; m < 4; m++) {
            af[m][0] = Alds[wm * 4 + m][0][lane];
            af[m][1] = Alds[wm * 4 + m][1][lane];
        }
        #pragma unroll
        for (int m = 0; m < 4; m++)
            #pragma unroll
            for (int n = 0; n < 4; n++) {
                acc[m][n] = __builtin_amdgcn_mfma_f32_16x16x32_bf16(af[m][1], bfr[n][0], acc[m][n], 0, 0, 0);
                acc[m][n] = __builtin_amdgcn_mfma_f32_16x16x32_bf16(af[m][0], bfr[n][1], acc[m][n], 0, 0, 0);
                acc[m][n] = __builtin_amdgcn_mfma_f32_16x16x32_bf16(af[m][0], bfr[n][0], acc[m][n], 0, 0, 0);
            }
        __syncthreads();
    }

    int r0 = row0 + wm * 64;
    int c0 = cb * 128 + wn * 64;
    #pragma unroll
    for (int m = 0; m < 4; m++)
        #pragma unroll
        for (int n = 0; n < 4; n++) {
            #pragma unroll
            for (int reg = 0; reg < 4; reg++) {
                int gr = r0 + m * 16 + (lane >> 4) * 4 + reg;
                int gc = c0 + n * 16 + (lane & 15);
                if (gr < M && gc < NW) {
                    if (gc < WDIM) {
                        float v = acc[m][n][reg] + bl[gc];
                        int head = gc / 100;
                        int fh = gc - head * 100;
                        __bf16 b = (__bf16)v;
                        Cl16[(size_t)gr * XLP + head * 128 + fh] = *(ushort*)&b;
                    } else {
                        int cc = gc - WDIM;
                        Cr[(size_t)gr * WDIM + cc] = acc[m][n][reg] + br[cc];
                    }
                }
            }
        }
}

// ---------------- fused GAT: parity-packed reduce, degree-sorted nodes ----
__device__ __forceinline__ f32x2 bf2f2(unsigned u) {
    f32x2 r;
    r.x = __uint_as_float(u << 16);
    r.y = __uint_as_float(u & 0xffff0000u);
    return r;
}
__device__ __forceinline__ f32x2 lrelu2(f32x2 t) {
    return __builtin_elementwise_max(t, t * BCAST2(NEG));
}

__global__ __launch_bounds__(256) void gat_edge_agg(
    const ushort* __restrict__ xl, const float* __restrict__ xr,
    const int* __restrict__ offsets, const int* __restrict__ csr_off,
    const int* __restrict__ order,
    const float* __restrict__ att, const float* __restrict__ bias,
    float* __restrict__ fout) {
    __shared__ float st[4][64][10];
    int wid  = threadIdx.x >> 6;
    int lane = threadIdx.x & 63;
    int node = order[blockIdx.x * 2 + (wid >> 1)];
    int sub  = wid & 1;
    int lq    = lane & 31;
    int headq = lane >> 5;   // 0 or 1
    int par   = lane & 1;

    f32x2 aw4[2] = {}, xr4[2] = {}, awp = {}, xrp = {};
    if (lq < 25) {
        float4 a = *(const float4*)(att + headq * 100 + 4 * lq);
        float4 b = *(const float4*)(xr + (size_t)node * WDIM + headq * 100 + 4 * lq);
        aw4[0] = (f32x2){a.x, a.y}; aw4[1] = (f32x2){a.z, a.w};
        xr4[0] = (f32x2){b.x, b.y}; xr4[1] = (f32x2){b.z, b.w};
    }
    if (lane < 50) {
        float2 a = *(const float2*)(att + 200 + 2 * lane);
        float2 b = *(const float2*)(xr + (size_t)node * WDIM + 200 + 2 * lane);
        awp = (f32x2){a.x, a.y};
        xrp = (f32x2){b.x, b.y};
    }

    float m_h = -1e38f, s_h = 0.f, m_2 = -1e38f, s_2 = 0.f;  // s parity-packed
    f32x2 acc4[2] = {}, accp = {};

    int beg = offsets[node], end = offsets[node + 1];
    int half = (end - beg + 1) >> 1;
    int lo = beg + sub * half;
    int iend = sub ? end : beg + half;

    for (int i = lo; i < iend; i += 2) {
        bool act_b = (i + 1) < iend;
        int oa = csr_off[i];
        int ob = csr_off[act_b ? i + 1 : i];
        uint2 ua = *(const uint2*)(xl + oa + 4 * lane);
        uint2 ub = *(const uint2*)(xl + ob + 4 * lane);
        unsigned pa = *(const unsigned*)(xl + oa + 256 + 2 * lane);
        unsigned pb = *(const unsigned*)(xl + ob + 256 + 2 * lane);

        f32x2 va0 = bf2f2(ua.x), va1 = bf2f2(ua.y), vap = bf2f2(pa);
        f32x2 vb0 = bf2f2(ub.x), vb1 = bf2f2(ub.y), vbp = bf2f2(pb);

        // packed dot: q = sum(lrelu(v+xr)*aw)
        f32x2 tA = __builtin_elementwise_fma(lrelu2(va0 + xr4[0]), aw4[0],
                                             lrelu2(va1 + xr4[1]) * aw4[1]);
        f32x2 tB = __builtin_elementwise_fma(lrelu2(vb0 + xr4[0]), aw4[0],
                                             lrelu2(vb1 + xr4[1]) * aw4[1]);
        f32x2 tA2 = lrelu2(vap + xrp) * awp;
        f32x2 tB2 = lrelu2(vbp + xrp) * awp;
        float qA  = tA.x + tA.y,   qB  = tB.x + tB.y;
        float qA2 = tA2.x + tA2.y, qB2 = tB2.x + tB2.y;

        // parity-packed reduce: stage1 per edge, pack by lane&1, shared stages
        qA += __shfl_xor(qA, 1, 64);   qB += __shfl_xor(qB, 1, 64);
        float u = par ? qB : qA;
        u += __shfl_xor(u, 2, 64);
        u += __shfl_xor(u, 4, 64);
        u += __shfl_xor(u, 8, 64);
        u += __shfl_xor(u, 16, 64);            // u: qA(even)/qB(odd), per half
        qA2 += __shfl_xor(qA2, 1, 64); qB2 += __shfl_xor(qB2, 1, 64);
        float v = par ? qB2 : qA2;
        v += __shfl_xor(v, 2, 64);
        v += __shfl_xor(v, 4, 64);
        v += __shfl_xor(v, 8, 64);
        v += __shfl_xor(v, 16, 64);
        v += __shfl_xor(v, 32, 64);            // v: qA2(even)/qB2(odd)
        if (!act_b && par) { u = -3e38f; v = -3e38f; }  // kill dead B stream

        float upair = fmaxf(u, __shfl_xor(u, 1, 64));   // pair-uniform max
        float vpair = fmaxf(v, __shfl_xor(v, 1, 64));

        // defer-rescale (THR=8); m uniform, s/acc scale shared
        if (__any(upair > m_h + 8.f || vpair > m_2 + 8.f)) {
            float nm_h = fmaxf(m_h, upair), nm_2 = fmaxf(m_2, vpair);
            float e_h = __expf(m_h - nm_h), e_2 = __expf(m_2 - nm_2);
            s_h *= e_h; s_2 *= e_2;
            acc4[0] *= BCAST2(e_h); acc4[1] *= BCAST2(e_h);
            accp *= BCAST2(e_2);
            m_h = nm_h; m_2 = nm_2;
        }
        float cu = __expf(u - m_h);   // packed coefficient (0 for dead stream)
        float cv = __expf(v - m_2);
        s_h += cu; s_2 += cv;         // parity-packed sums
        float cup = __shfl_xor(cu, 1, 64), cvp = __shfl_xor(cv, 1, 64);
        float cA  = par ? cup : cu;
        float cB  = par ? cu  : cup;
        float cA2 = par ? cvp : cv;
        float cB2 = par ? cv  : cvp;
        acc4[0] = __builtin_elementwise_fma(BCAST2(cA), va0, acc4[0]);
        acc4[1] = __builtin_elementwise_fma(BCAST2(cA), va1, acc4[1]);
        acc4[0] = __builtin_elementwise_fma(BCAST2(cB), vb0, acc4[0]);
        acc4[1] = __builtin_elementwise_fma(BCAST2(cB), vb1, acc4[1]);
        accp    = __builtin_elementwise_fma(BCAST2(cA2), vap, accp);
        accp    = __builtin_elementwise_fma(BCAST2(cB2), vbp, accp);
    }

    // merge parity-packed sums before publishing
    s_h += __shfl_xor(s_h, 1, 64);
    s_2 += __shfl_xor(s_2, 1, 64);

    // publish partial state
    st[wid][lane][0] = m_h; st[wid][lane][1] = s_h;
    st[wid][lane][2] = m_2; st[wid][lane][3] = s_2;
    st[wid][lane][4] = acc4[0].x; st[wid][lane][5] = acc4[0].y;
    st[wid][lane][6] = acc4[1].x; st[wid][lane][7] = acc4[1].y;
    st[wid][lane][8] = accp.x;    st[wid][lane][9] = accp.y;
    __syncthreads();
    if (sub) return;

    // exact merge with partner wave (lane-local, no shuffles)
    const float* p = st[wid ^ 1][lane];
    float pm_h = p[0], ps_h = p[1], pm_2 = p[2], ps_2 = p[3];

    float M_h = fmaxf(m_h, pm_h);
    float ea_h = __expf(m_h - M_h), eb_h = __expf(pm_h - M_h);
    float inv_h = 1.f / (s_h * ea_h + ps_h * eb_h);
    float M_2 = fmaxf(m_2, pm_2);
    float ea_2 = __expf(m_2 - M_2), eb_2 = __expf(pm_2 - M_2);
    float inv_2 = 1.f / (s_2 * ea_2 + ps_2 * eb_2);

    if (lq < 25) {
        float4 bv = *(const float4*)(bias + headq * 100 + 4 * lq);
        float4 o;
        o.x = fmaxf((acc4[0].x * ea_h + p[4] * eb_h) * inv_h + bv.x, 0.f);
        o.y = fmaxf((acc4[0].y * ea_h + p[5] * eb_h) * inv_h + bv.y, 0.f);
        o.z = fmaxf((acc4[1].x * ea_h + p[6] * eb_h) * inv_h + bv.z, 0.f);
        o.w = fmaxf((acc4[1].y * ea_h + p[7] * eb_h) * inv_h + bv.w, 0.f);
        *(float4*)(fout + (size_t)node * WDIM + headq * 100 + 4 * lq) = o;
    }
    if (lane < 50) {
        float2 bv = *(const float2*)(bias + 200 + 2 * lane);
        float2 o;
        o.x = fmaxf((accp.x * ea_2 + p[8] * eb_2) * inv_2 + bv.x, 0.f);
        o.y = fmaxf((accp.y * ea_2 + p[9] * eb_2) * inv_2 + bv.y, 0.f);
        *(float2*)(fout + (size_t)node * WDIM + 200 + 2 * lane) = o;
    }
}

// ---------------- host ----------------
static inline size_t align256(size_t x) { return (x + 255) & ~(size_t)255; }

extern "C" void kernel_launch(void* const* d_in, const int* in_sizes, int n_in,
                              void* d_out, int out_size, void* d_ws, size_t ws_size,
                              hipStream_t stream) {
    const int*   x     = (const int*)d_in[0];
    const int*   ei    = (const int*)d_in[1];
    const float* emb   = (const float*)d_in[2];
    const float* Wl0   = (const float*)d_in[3];
    const float* bl0   = (const float*)d_in[4];
    const float* Wr0   = (const float*)d_in[5];
    const float* br0   = (const float*)d_in[6];
    const float* att0  = (const float*)d_in[7];
    const float* bias0 = (const float*)d_in[8];
    const float* Wl    = (const float*)d_in[9];
    const float* bl    = (const float*)d_in[10];
    const float* Wr    = (const float*)d_in[11];
    const float* br    = (const float*)d_in[12];
    const float* att   = (const float*)d_in[13];
    const float* bias  = (const float*)d_in[14];

    char* ws = (char*)d_ws;
    size_t off = 0;
    float* h      = (float*)(ws + off);  off = align256(off + (size_t)NODES * WDIM * 4);
    ushort* xlb16 = (ushort*)(ws + off); off = align256(off + (size_t)NODES * XLP * 2);
    float* xrb    = (float*)(ws + off);  off = align256(off + (size_t)NODES * WDIM * 4);
    // contiguous zero-init region: counts | cursor | hist | dcur  (one memset)
    int* counts   = (int*)(ws + off);    off += (size_t)NODES * 4;
    int* cursor   = (int*)(ws + off);    off += (size_t)NODES * 4;
    int* hist     = (int*)(ws + off);    off += (size_t)NBIN * 4;
    int* dcur     = (int*)(ws + off);    off = align256(off + (size_t)NBIN * 4);
    size_t zero_bytes = (size_t)(2 * NODES + 2 * NBIN) * 4;
    int* offsets  = (int*)(ws + off);    off = align256(off + (size_t)(NODES + 1) * 4);
    int* csr_off  = (int*)(ws + off);    off = align256(off + (size_t)ETOT * 4);
    int* doffs    = (int*)(ws + off);    off = align256(off + (size_t)(NBIN + 1) * 4);
    int* order    = (int*)(ws + off);    off = align256(off + (size_t)NODES * 4);
    size_t frag_l0_elems = (size_t)4 * 40 * 2 * 64;    // bf16x8 units
    size_t frag_ln_elems = (size_t)10 * 40 * 2 * 64;
    bf16x8* bfrag0 = (bf16x8*)(ws + off); off = align256(off + frag_l0_elems * 16);
    bf16x8* bfrag1 = (bf16x8*)(ws + off); off = align256(off + 4 * frag_ln_elems * 16);

    float* out = (float*)d_out;

    // all weight fragment pre-splits in ONE launch
    {
        int total = 4 * 40 * 64 + 4 * 10 * 40 * 64;
        make_bfrag_all<<<(total + 255) / 256, 256, 0, stream>>>(
            Wl0, Wr0, Wl, Wr, bfrag0, bfrag1, frag_ln_elems);
    }

    // CSR build (single fused memset for all four zeroed buffers)
    hipMemsetAsync(counts, 0, zero_bytes, stream);
    count_edges<<<(ETOT + 255) / 256, 256, 0, stream>>>(ei, counts);
    scan_kernel<<<1, 1024, 0, stream>>>(counts, offsets, NODES);
    scatter_edges<<<(ETOT + 255) / 256, 256, 0, stream>>>(ei, offsets, cursor, csr_off);

    // degree sort (descending) for balanced agg blocks
    hist_deg<<<(NODES + 255) / 256, 256, 0, stream>>>(counts, hist);
    scan_kernel<<<1, 1024, 0, stream>>>(hist, doffs, NBIN);
    scatter_deg<<<(NODES + 255) / 256, 256, 0, stream>>>(counts, doffs, dcur, order);

    int agg_blocks = NODES / 2;   // 2 nodes per block (NODES even)

    // layer 0: A = emb with row indirection
    gemm_mfma<<<1200, 256, 0, stream>>>(emb, x, 1, bfrag0, bl0, br0, xlb16, xrb, NODES, D0, 4);
    gat_edge_agg<<<agg_blocks, 256, 0, stream>>>(xlb16, xrb, offsets, csr_off, order,
                                                 att0, bias0, h);

    // layers 1..4
    for (int i = 0; i < 4; i++) {
        float* dst = (i == 3) ? out : h;
        gemm_mfma<<<1200, 256, 0, stream>>>(h, nullptr, 0, bfrag1 + i * frag_ln_elems,
                                            bl + i * WDIM, br + i * WDIM,
                                            xlb16, xrb, NODES, WDIM, 10);
        gat_edge_agg<<<agg_blocks, 256, 0, stream>>>(xlb16, xrb, offsets, csr_off, order,
                                                     att + (size_t)i * WDIM,
                                                     bias + (size_t)i * WDIM, dst);
    }
}